// Round 8
// baseline (215.125 us; speedup 1.0000x reference)
//
#include <hip/hip_runtime.h>

typedef unsigned short u16;
typedef __bf16 bfloat;
typedef bfloat bf16x8 __attribute__((ext_vector_type(8)));
typedef float f32x4 __attribute__((ext_vector_type(4)));
typedef u16 v8u16 __attribute__((ext_vector_type(8)));
typedef u16 v4u16 __attribute__((ext_vector_type(4)));

#define B_ 32
#define L_ 200
#define D_ 512
#define H_ 8
#define HD_ 64
#define M_ (B_*L_)   // 6400 tokens

__device__ __forceinline__ float bf2f(u16 u) {
  union { float f; unsigned int i; } v; v.i = ((unsigned int)u) << 16; return v.f;
}
__device__ __forceinline__ u16 f2bf(float f) {
  union { float f; unsigned int i; } v; v.f = f;
  unsigned int i = v.i;
  return (u16)((i + 0x7FFFu + ((i >> 16) & 1u)) >> 16);
}
__device__ __forceinline__ bf16x8 as_bf(v8u16 v) { return __builtin_bit_cast(bf16x8, v); }

__device__ __forceinline__ void gload16(const void* g, void* l) {
  __builtin_amdgcn_global_load_lds(
      (const __attribute__((address_space(1))) void*)g,
      (__attribute__((address_space(3))) void*)l,
      16, 0, 0);
}

struct TPtrs { const float* s[12]; };

// ---------------- prep: qb = bf16(x*valid)  (blocks 0..1599)
//                   + W[k][n] fp32 -> Wt[n][k] bf16 (blocks 1600..2367) ----------------
__global__ __launch_bounds__(256) void prep_kernel(
    const float* __restrict__ x, const unsigned char* __restrict__ mask,
    u16* __restrict__ qb, TPtrs tp, u16* __restrict__ dst)
{
  __shared__ float T[64][65];
  int bid = blockIdx.x;
  int t = threadIdx.x;
  if (bid < 1600) {
    size_t i = (size_t)bid * 256 + t;
    size_t base = i * 8;
    int tok = (int)(base >> 9);
    float valid = mask[tok] ? 0.f : 1.f;
    float4 v0 = *(const float4*)(x + base);
    float4 v1 = *(const float4*)(x + base + 4);
    v8u16 ob;
    ob[0]=f2bf(v0.x*valid); ob[1]=f2bf(v0.y*valid); ob[2]=f2bf(v0.z*valid); ob[3]=f2bf(v0.w*valid);
    ob[4]=f2bf(v1.x*valid); ob[5]=f2bf(v1.y*valid); ob[6]=f2bf(v1.z*valid); ob[7]=f2bf(v1.w*valid);
    *(v8u16*)(qb + base) = ob;
  } else {
    int wb   = bid - 1600;
    int mat  = wb >> 6;
    int tile = wb & 63;
    int tr = tile >> 3, tc = tile & 7;
    const float* src = tp.s[mat];
    #pragma unroll
    for (int i = 0; i < 4; i++) {
      int idx = t + i * 256;
      int row = idx >> 4, c4 = idx & 15;
      float4 v = *(const float4*)(src + (size_t)(tr * 64 + row) * 512 + tc * 64 + c4 * 4);
      T[row][c4 * 4 + 0] = v.x; T[row][c4 * 4 + 1] = v.y;
      T[row][c4 * 4 + 2] = v.z; T[row][c4 * 4 + 3] = v.w;
    }
    __syncthreads();
    u16* d = dst + (size_t)mat * 262144;
    #pragma unroll
    for (int i = 0; i < 2; i++) {
      int idx = t + i * 256;
      int row = idx >> 3, c8 = idx & 7;
      v8u16 v;
      #pragma unroll
      for (int j = 0; j < 8; j++) v[j] = f2bf(T[c8 * 8 + j][row]);
      *(v8u16*)(d + (size_t)(tc * 64 + row) * 512 + tr * 64 + c8 * 8) = v;
    }
  }
}

// ---------------- LayerNorm: bf16 in, bf16 or fp32 out, row over D=512 ----------------
template<bool OUTF32>
__global__ __launch_bounds__(256) void ln_kernel(
    const u16* __restrict__ in, const float* __restrict__ g, const float* __restrict__ b,
    u16* __restrict__ outb, float* __restrict__ outf)
{
  int row  = blockIdx.x * 4 + (threadIdx.x >> 6);
  int lane = threadIdx.x & 63;
  size_t base = (size_t)row * 512 + lane * 8;
  v8u16 xv = *(const v8u16*)(in + base);
  float xs[8];
  #pragma unroll
  for (int j = 0; j < 8; j++) xs[j] = bf2f(xv[j]);
  float s = 0.f, q = 0.f;
  #pragma unroll
  for (int j = 0; j < 8; j++) { s += xs[j]; q += xs[j] * xs[j]; }
  #pragma unroll
  for (int off = 1; off < 64; off <<= 1) { s += __shfl_xor(s, off); q += __shfl_xor(q, off); }
  float mean = s * (1.f / 512.f);
  float var  = fmaxf(q * (1.f / 512.f) - mean * mean, 0.f);
  float rstd = rsqrtf(var + 1e-8f);
  float4 g0 = *(const float4*)(g + lane * 8);
  float4 g1 = *(const float4*)(g + lane * 8 + 4);
  float4 b0 = *(const float4*)(b + lane * 8);
  float4 b1 = *(const float4*)(b + lane * 8 + 4);
  float gv[8] = {g0.x,g0.y,g0.z,g0.w,g1.x,g1.y,g1.z,g1.w};
  float bv[8] = {b0.x,b0.y,b0.z,b0.w,b1.x,b1.y,b1.z,b1.w};
  if (OUTF32) {
    float of[8];
    #pragma unroll
    for (int j = 0; j < 8; j++) of[j] = (xs[j] - mean) * rstd * gv[j] + bv[j];
    *(float4*)(outf + base)     = make_float4(of[0], of[1], of[2], of[3]);
    *(float4*)(outf + base + 4) = make_float4(of[4], of[5], of[6], of[7]);
  } else {
    v8u16 ob;
    #pragma unroll
    for (int j = 0; j < 8; j++) ob[j] = f2bf((xs[j] - mean) * rstd * gv[j] + bv[j]);
    *(v8u16*)(outb + base) = ob;
  }
}

// ---------------- GEMM core (r6-proven): acc[2][4] for a 64x128 tile, K=512, BK=64.
// Single-buffer global_load_lds staging, 2 barriers/K-step.
// LDS swizzle: granule g of row r stored at g^(r&7) (applied on global src + LDS read).
__device__ __forceinline__ void gemm_core(
    const u16* __restrict__ A, const u16* __restrict__ Wt,
    int m0, int n0, u16* As, u16* Bs, f32x4 (&acc)[2][4])
{
  int tid = threadIdx.x, wid = tid >> 6, lane = tid & 63;
  int wr = wid >> 1, wc = wid & 1;
  int l15 = lane & 15, hi = lane >> 4;
  int sr8 = lane >> 3;            // 0..7 row within 8-row group
  int gsw = (lane & 7) ^ sr8;     // swizzled source granule

  for (int s = 0; s < 8; s++) {
    int kk = s * 64;
    #pragma unroll
    for (int i = 0; i < 2; i++) {
      int rb = i * 32 + wid * 8;
      gload16(A + (size_t)(m0 + rb + sr8) * 512 + kk + gsw * 8, (char*)As + rb * 128);
    }
    #pragma unroll
    for (int j = 0; j < 4; j++) {
      int rb = j * 32 + wid * 8;
      gload16(Wt + (size_t)(n0 + rb + sr8) * 512 + kk + gsw * 8, (char*)Bs + rb * 128);
    }
    __syncthreads();
    #pragma unroll
    for (int ksub = 0; ksub < 2; ksub++) {
      int ga = ksub * 4 + hi;
      bf16x8 af[2], bfr[4];
      #pragma unroll
      for (int mi = 0; mi < 2; mi++) {
        int ra = wr * 32 + mi * 16 + l15;
        af[mi] = *(const bf16x8*)(As + ra * 64 + ((ga ^ (ra & 7)) * 8));
      }
      #pragma unroll
      for (int ni = 0; ni < 4; ni++) {
        int rb = wc * 64 + ni * 16 + l15;
        bfr[ni] = *(const bf16x8*)(Bs + rb * 64 + ((ga ^ (rb & 7)) * 8));
      }
      #pragma unroll
      for (int mi = 0; mi < 2; mi++)
        #pragma unroll
        for (int ni = 0; ni < 4; ni++)
          acc[mi][ni] = __builtin_amdgcn_mfma_f32_16x16x32_bf16(af[mi], bfr[ni], acc[mi][ni], 0, 0, 0);
    }
    __syncthreads();
  }
}

// single GEMM: grid 400 (100 M-tiles x 4 N-tiles)
template<bool RELU, bool HAS_RES, bool MASK>
__global__ __launch_bounds__(256) void gemm_one(
    const u16* __restrict__ A, const u16* __restrict__ Wt, const float* __restrict__ bias,
    const u16* __restrict__ res, const unsigned char* __restrict__ mask,
    u16* __restrict__ outb)
{
  __shared__ u16 As[64 * 64];
  __shared__ u16 Bs[128 * 64];
  int bid = blockIdx.x;
  int m0 = (bid >> 2) * 64, n0 = (bid & 3) * 128;
  f32x4 acc[2][4] = {};
  gemm_core(A, Wt, m0, n0, As, Bs, acc);

  int tid = threadIdx.x, wid = tid >> 6, lane = tid & 63;
  int wr = wid >> 1, wc = wid & 1;
  int l15 = lane & 15, hi = lane >> 4;
  #pragma unroll
  for (int ni = 0; ni < 4; ni++) {
    int gc = n0 + wc * 64 + ni * 16 + l15;
    float bvv = bias[gc];
    #pragma unroll
    for (int mi = 0; mi < 2; mi++) {
      int grb = m0 + wr * 32 + mi * 16 + hi * 4;
      #pragma unroll
      for (int r = 0; r < 4; r++) {
        int gr = grb + r;
        float v = acc[mi][ni][r] + bvv;
        if (HAS_RES) v += bf2f(res[(size_t)gr * 512 + gc]);
        if (RELU) v = fmaxf(v, 0.f);
        if (MASK) v = mask[gr] ? 0.f : v;
        outb[(size_t)gr * 512 + gc] = f2bf(v);
      }
    }
  }
}

// merged Q,K,V GEMMs: grid 1200. V written directly in transposed Vt layout.
__global__ __launch_bounds__(256) void gemm_qkv(
    const u16* __restrict__ Aq, const u16* __restrict__ Akv,
    const u16* __restrict__ Wtq, const u16* __restrict__ Wtk, const u16* __restrict__ Wtv,
    const float* __restrict__ bq, const float* __restrict__ bk, const float* __restrict__ bv,
    u16* __restrict__ outq, u16* __restrict__ outk, u16* __restrict__ outvt)
{
  __shared__ u16 As[64 * 64];
  __shared__ u16 Bs[128 * 64];
  int bid = blockIdx.x;
  int mat = bid / 400;
  int rr = bid - mat * 400;
  int m0 = (rr >> 2) * 64, n0 = (rr & 3) * 128;
  const u16*   A    = (mat == 0) ? Aq  : Akv;
  const u16*   Wt   = (mat == 0) ? Wtq : ((mat == 1) ? Wtk : Wtv);
  const float* bias = (mat == 0) ? bq  : ((mat == 1) ? bk  : bv);
  f32x4 acc[2][4] = {};
  gemm_core(A, Wt, m0, n0, As, Bs, acc);

  int tid = threadIdx.x, wid = tid >> 6, lane = tid & 63;
  int wr = wid >> 1, wc = wid & 1;
  int l15 = lane & 15, hi = lane >> 4;
  if (mat == 2) {
    // Vt[b,h,hd(64), l(224)] transposed write; pad cols [200,224) untouched (P is 0 there)
    #pragma unroll
    for (int ni = 0; ni < 4; ni++) {
      int gc = n0 + wc * 64 + ni * 16 + l15;
      float bvv = bias[gc];
      int h = gc >> 6, hd = gc & 63;
      #pragma unroll
      for (int mi = 0; mi < 2; mi++) {
        int grb = m0 + wr * 32 + mi * 16 + hi * 4;
        #pragma unroll
        for (int r = 0; r < 4; r++) {
          int gr = grb + r;
          int b = gr / 200, l = gr - b * 200;
          outvt[((size_t)(b * 8 + h) * 64 + hd) * 224 + l] = f2bf(acc[mi][ni][r] + bvv);
        }
      }
    }
  } else {
    u16* outb = (mat == 0) ? outq : outk;
    #pragma unroll
    for (int ni = 0; ni < 4; ni++) {
      int gc = n0 + wc * 64 + ni * 16 + l15;
      float bvv = bias[gc];
      #pragma unroll
      for (int mi = 0; mi < 2; mi++) {
        int grb = m0 + wr * 32 + mi * 16 + hi * 4;
        #pragma unroll
        for (int r = 0; r < 4; r++) {
          int gr = grb + r;
          outb[(size_t)gr * 512 + gc] = f2bf(acc[mi][ni][r] + bvv);
        }
      }
    }
  }
}

// ---------------- attention: 2 WGs per (b,h), 4 waves each; K swizzled, V in padded LDS.
// WG g=0: waves handle tiles (12,0),(11,1),(10,2),(9,3); g=1: (8,4),(7,5),(6,-),(-,-).
__global__ __launch_bounds__(256) void attn_kernel(
    const u16* __restrict__ Qh, const u16* __restrict__ Kh,
    const u16* __restrict__ Vt, u16* __restrict__ ctx)
{
  __shared__ u16 Kl[208 * 64];       // granule-swizzled rows
  __shared__ u16 Vl[64 * 232];       // padded stride
  __shared__ u16 Pl[4 * 16 * 232];   // per-wave P, padded stride
  int bid = blockIdx.x;
  int bh = bid >> 1, g = bid & 1;
  int b = bh >> 3, h = bh & 7;
  int tid = threadIdx.x;
  int wid = tid >> 6, lane = tid & 63;

  // stage K with pre-swizzled source granule (gload16: linear LDS dest)
  int krows = g ? 144 : 208;
  const u16* Kg = Kh + (size_t)(b * L_) * D_ + h * HD_;
  int nchunks = krows * 8;          // 16B chunks
  for (int base = 0; base < nchunks; base += 256) {
    int idx = base + tid;
    if (idx < nchunks) {
      int row = idx >> 3, gr = idx & 7;
      int gsrc = gr ^ (row & 7);
      gload16(Kg + (size_t)row * D_ + gsrc * 8, (char*)Kl + idx * 16);
    }
  }
  // stage V [64][224] -> Vl [64][232]
  const u16* Vg = Vt + (size_t)bh * 64 * 224;
  for (int idx = tid; idx < 64 * 28; idx += 256) {
    int row = idx / 28, c = idx - row * 28;
    v8u16 v = *(const v8u16*)(Vg + row * 224 + c * 8);
    *(v8u16*)(Vl + row * 232 + c * 8) = v;
  }
  __syncthreads();

  int l15 = lane & 15, hi = lane >> 4;
  u16* Pw = Pl + wid * 16 * 232;
  {
    v4u16 z4 = {0,0,0,0};
    *(v4u16*)(Pw + l15 * 232 + 208 + hi * 4) = z4;   // zero cols 208..223
  }

  int tA, tB;
  if (g == 0) { tA = 12 - wid; tB = wid; }
  else        { tA = (wid < 3) ? 8 - wid : -1; tB = (wid < 2) ? 4 + wid : -1; }

  for (int j = 0; j < 2; j++) {
    int t = j ? tB : tA;
    if (t < 0) continue;
    int q0 = t * 16;
    int qrow = q0 + l15; if (qrow > L_ - 1) qrow = L_ - 1;
    const u16* Qg = Qh + (size_t)(b * L_ + qrow) * D_ + h * HD_ + hi * 8;
    bf16x8 aq0 = as_bf(*(const v8u16*)(Qg));
    bf16x8 aq1 = as_bf(*(const v8u16*)(Qg + 32));

    f32x4 sv[13];
    float m0[4];
    #pragma unroll
    for (int r = 0; r < 4; r++) m0[r] = -3.0e38f;

    #pragma unroll
    for (int kt = 0; kt < 13; kt++) {
      if (kt <= t) {                    // wave-uniform causal trim
        int row = kt * 16 + l15;
        const u16* kp = Kl + row * 64;
        bf16x8 bk0 = as_bf(*(const v8u16*)(kp + ((hi       ^ (row & 7)) * 8)));
        bf16x8 bk1 = as_bf(*(const v8u16*)(kp + (((4 + hi) ^ (row & 7)) * 8)));
        f32x4 a = {0.f, 0.f, 0.f, 0.f};
        a = __builtin_amdgcn_mfma_f32_16x16x32_bf16(aq0, bk0, a, 0, 0, 0);
        a = __builtin_amdgcn_mfma_f32_16x16x32_bf16(aq1, bk1, a, 0, 0, 0);
        #pragma unroll
        for (int r = 0; r < 4; r++) {
          int qr = q0 + hi * 4 + r;
          int kc = kt * 16 + l15;
          float val = (kc <= qr && qr < L_) ? a[r] * 0.125f : -3.0e38f;
          sv[kt][r] = val;
          m0[r] = fmaxf(m0[r], val);
        }
      } else {
        #pragma unroll
        for (int r = 0; r < 4; r++) sv[kt][r] = -3.0e38f;
      }
    }
    #pragma unroll
    for (int r = 0; r < 4; r++) {
      #pragma unroll
      for (int off = 1; off < 16; off <<= 1)
        m0[r] = fmaxf(m0[r], __shfl_xor(m0[r], off));
      if (m0[r] < -1e37f) m0[r] = 0.f;
    }
    float sum[4] = {0.f, 0.f, 0.f, 0.f};
    #pragma unroll
    for (int kt = 0; kt < 13; kt++) {
      if (kt <= t) {
        #pragma unroll
        for (int r = 0; r < 4; r++) {
          float p = __expf(sv[kt][r] - m0[r]);
          sv[kt][r] = p;
          sum[r] += p;
        }
      } else {
        #pragma unroll
        for (int r = 0; r < 4; r++) sv[kt][r] = 0.f;
      }
    }
    #pragma unroll
    for (int r = 0; r < 4; r++) {
      #pragma unroll
      for (int off = 1; off < 16; off <<= 1) sum[r] += __shfl_xor(sum[r], off);
    }
    float inv[4];
    #pragma unroll
    for (int r = 0; r < 4; r++) inv[r] = sum[r] > 0.f ? 1.f / sum[r] : 0.f;

    #pragma unroll
    for (int kt = 0; kt < 13; kt++) {
      #pragma unroll
      for (int r = 0; r < 4; r++)
        Pw[(hi * 4 + r) * 232 + kt * 16 + l15] = f2bf(sv[kt][r]);
    }

    int ksmax = (t + 2) >> 1;   // PV k-slots with nonzero P
    #pragma unroll
    for (int nt = 0; nt < 4; nt++) {
      f32x4 a = {0.f, 0.f, 0.f, 0.f};
      #pragma unroll
      for (int ks = 0; ks < 7; ks++) {
        if (ks < ksmax) {
          bf16x8 ap = as_bf(*(const v8u16*)(Pw + l15 * 232 + ks * 32 + hi * 8));
          bf16x8 bv = as_bf(*(const v8u16*)(Vl + (nt * 16 + l15) * 232 + ks * 32 + hi * 8));
          a = __builtin_amdgcn_mfma_f32_16x16x32_bf16(ap, bv, a, 0, 0, 0);
        }
      }
      #pragma unroll
      for (int r = 0; r < 4; r++) {
        int qr = q0 + hi * 4 + r;
        if (qr < L_) ctx[(size_t)(b * L_ + qr) * D_ + h * HD_ + nt * 16 + l15] = f2bf(a[r] * inv[r]);
      }
    }
  }
}

// ---------------- host ----------------
extern "C" void kernel_launch(void* const* d_in, const int* in_sizes, int n_in,
                              void* d_out, int out_size, void* d_ws, size_t ws_size,
                              hipStream_t stream)
{
  (void)in_sizes; (void)n_in; (void)out_size; (void)ws_size;
  const float* x    = (const float*)d_in[0];
  const unsigned char* mask = (const unsigned char*)d_in[1];
  const float* ln1g = (const float*)d_in[2];
  const float* ln1b = (const float*)d_in[3];
  const float* Wq   = (const float*)d_in[4];
  const float* bq   = (const float*)d_in[5];
  const float* Wk   = (const float*)d_in[6];
  const float* bk   = (const float*)d_in[7];
  const float* Wv   = (const float*)d_in[8];
  const float* bv   = (const float*)d_in[9];
  const float* Wo   = (const float*)d_in[10];
  const float* bo   = (const float*)d_in[11];
  const float* ln2g = (const float*)d_in[12];
  const float* ln2b = (const float*)d_in[13];
  const float* W1   = (const float*)d_in[14];
  const float* b1   = (const float*)d_in[15];
  const float* W2   = (const float*)d_in[16];
  const float* b2   = (const float*)d_in[17];
  const float* lnfg = (const float*)d_in[18];
  const float* lnfb = (const float*)d_in[19];

  char* ws = (char*)d_ws;
  u16* Wt  = (u16*)(ws);                 //  6,291,456 B
  u16* qb  = (u16*)(ws +  6291456);      //  6,553,600 B  current q (bf16)
  u16* Qn  = (u16*)(ws + 12845056);      //  6,553,600 B  LN output
  u16* qh  = (u16*)(ws + 19398656);      //  6,553,600 B  qh / h1
  u16* kh  = (u16*)(ws + 25952256);      //  6,553,600 B  kh
  u16* vh  = (u16*)(ws + 32505856);      //  6,553,600 B  ctx
  u16* Vtb = (u16*)(ws + 39059456);      //  7,340,032 B  -> end 46,399,488

  TPtrs tp;
  tp.s[0] = Wq; tp.s[1] = Wq + 262144;
  tp.s[2] = Wk; tp.s[3] = Wk + 262144;
  tp.s[4] = Wv; tp.s[5] = Wv + 262144;
  tp.s[6] = Wo; tp.s[7] = Wo + 262144;
  tp.s[8] = W1; tp.s[9] = W1 + 262144;
  tp.s[10] = W2; tp.s[11] = W2 + 262144;

  prep_kernel<<<dim3(2368), dim3(256), 0, stream>>>(x, mask, qb, tp, Wt);

  for (int i = 0; i < 2; i++) {
    const u16* Wtq = Wt + (size_t)(0 + i) * 262144;
    const u16* Wtk = Wt + (size_t)(2 + i) * 262144;
    const u16* Wtv = Wt + (size_t)(4 + i) * 262144;
    const u16* Wto = Wt + (size_t)(6 + i) * 262144;
    const u16* Wt1 = Wt + (size_t)(8 + i) * 262144;
    const u16* Wt2 = Wt + (size_t)(10 + i) * 262144;

    ln_kernel<false><<<dim3(1600), dim3(256), 0, stream>>>(qb, ln1g + i * 512, ln1b + i * 512, Qn, nullptr);
    gemm_qkv<<<dim3(1200), dim3(256), 0, stream>>>(Qn, qb, Wtq, Wtk, Wtv,
                                                   bq + i * 512, bk + i * 512, bv + i * 512,
                                                   qh, kh, Vtb);
    attn_kernel<<<dim3(512), dim3(256), 0, stream>>>(qh, kh, Vtb, vh);   // ctx -> vh
    gemm_one<false,true,false><<<dim3(400), dim3(256), 0, stream>>>(vh, Wto, bo + i * 512, Qn, nullptr, qb);
    ln_kernel<false><<<dim3(1600), dim3(256), 0, stream>>>(qb, ln2g + i * 512, ln2b + i * 512, Qn, nullptr);
    gemm_one<true,false,false><<<dim3(400), dim3(256), 0, stream>>>(Qn, Wt1, b1 + i * 512, nullptr, nullptr, qh);
    gemm_one<false,true,true><<<dim3(400), dim3(256), 0, stream>>>(qh, Wt2, b2 + i * 512, Qn, mask, qb);
  }
  ln_kernel<true><<<dim3(1600), dim3(256), 0, stream>>>(qb, lnfg, lnfb, nullptr, (float*)d_out);
}

// Round 9
// 196.318 us; speedup vs baseline: 1.0958x; 1.0958x over previous
//
#include <hip/hip_runtime.h>

typedef unsigned short u16;
typedef __bf16 bfloat;
typedef bfloat bf16x8 __attribute__((ext_vector_type(8)));
typedef float f32x4 __attribute__((ext_vector_type(4)));
typedef u16 v8u16 __attribute__((ext_vector_type(8)));
typedef u16 v4u16 __attribute__((ext_vector_type(4)));

#define B_ 32
#define L_ 200
#define D_ 512
#define H_ 8
#define HD_ 64
#define M_ (B_*L_)   // 6400 tokens

__device__ __forceinline__ float bf2f(u16 u) {
  union { float f; unsigned int i; } v; v.i = ((unsigned int)u) << 16; return v.f;
}
__device__ __forceinline__ u16 f2bf(float f) {
  union { float f; unsigned int i; } v; v.f = f;
  unsigned int i = v.i;
  return (u16)((i + 0x7FFFu + ((i >> 16) & 1u)) >> 16);
}
__device__ __forceinline__ bf16x8 as_bf(v8u16 v) { return __builtin_bit_cast(bf16x8, v); }

__device__ __forceinline__ void gload16(const void* g, void* l) {
  __builtin_amdgcn_global_load_lds(
      (const __attribute__((address_space(1))) void*)g,
      (__attribute__((address_space(3))) void*)l,
      16, 0, 0);
}

struct TPtrs { const float* s[12]; };

// ---------------- prep: qb = bf16(x*valid)  (blocks 0..1599)
//                   + W[k][n] fp32 -> Wt[n][k] bf16 (blocks 1600..2367) ----------------
__global__ __launch_bounds__(256) void prep_kernel(
    const float* __restrict__ x, const unsigned char* __restrict__ mask,
    u16* __restrict__ qb, TPtrs tp, u16* __restrict__ dst)
{
  __shared__ float T[64][65];
  int bid = blockIdx.x;
  int t = threadIdx.x;
  if (bid < 1600) {
    size_t i = (size_t)bid * 256 + t;
    size_t base = i * 8;
    int tok = (int)(base >> 9);
    float valid = mask[tok] ? 0.f : 1.f;
    float4 v0 = *(const float4*)(x + base);
    float4 v1 = *(const float4*)(x + base + 4);
    v8u16 ob;
    ob[0]=f2bf(v0.x*valid); ob[1]=f2bf(v0.y*valid); ob[2]=f2bf(v0.z*valid); ob[3]=f2bf(v0.w*valid);
    ob[4]=f2bf(v1.x*valid); ob[5]=f2bf(v1.y*valid); ob[6]=f2bf(v1.z*valid); ob[7]=f2bf(v1.w*valid);
    *(v8u16*)(qb + base) = ob;
  } else {
    int wb   = bid - 1600;
    int mat  = wb >> 6;
    int tile = wb & 63;
    int tr = tile >> 3, tc = tile & 7;
    const float* src = tp.s[mat];
    #pragma unroll
    for (int i = 0; i < 4; i++) {
      int idx = t + i * 256;
      int row = idx >> 4, c4 = idx & 15;
      float4 v = *(const float4*)(src + (size_t)(tr * 64 + row) * 512 + tc * 64 + c4 * 4);
      T[row][c4 * 4 + 0] = v.x; T[row][c4 * 4 + 1] = v.y;
      T[row][c4 * 4 + 2] = v.z; T[row][c4 * 4 + 3] = v.w;
    }
    __syncthreads();
    u16* d = dst + (size_t)mat * 262144;
    #pragma unroll
    for (int i = 0; i < 2; i++) {
      int idx = t + i * 256;
      int row = idx >> 3, c8 = idx & 7;
      v8u16 v;
      #pragma unroll
      for (int j = 0; j < 8; j++) v[j] = f2bf(T[c8 * 8 + j][row]);
      *(v8u16*)(d + (size_t)(tc * 64 + row) * 512 + tr * 64 + c8 * 8) = v;
    }
  }
}

// ---------------- LayerNorm: bf16 in, bf16 or fp32 out, row over D=512 ----------------
template<bool OUTF32>
__global__ __launch_bounds__(256) void ln_kernel(
    const u16* __restrict__ in, const float* __restrict__ g, const float* __restrict__ b,
    u16* __restrict__ outb, float* __restrict__ outf)
{
  int row  = blockIdx.x * 4 + (threadIdx.x >> 6);
  int lane = threadIdx.x & 63;
  size_t base = (size_t)row * 512 + lane * 8;
  v8u16 xv = *(const v8u16*)(in + base);
  float xs[8];
  #pragma unroll
  for (int j = 0; j < 8; j++) xs[j] = bf2f(xv[j]);
  float s = 0.f, q = 0.f;
  #pragma unroll
  for (int j = 0; j < 8; j++) { s += xs[j]; q += xs[j] * xs[j]; }
  #pragma unroll
  for (int off = 1; off < 64; off <<= 1) { s += __shfl_xor(s, off); q += __shfl_xor(q, off); }
  float mean = s * (1.f / 512.f);
  float var  = fmaxf(q * (1.f / 512.f) - mean * mean, 0.f);
  float rstd = rsqrtf(var + 1e-8f);
  float4 g0 = *(const float4*)(g + lane * 8);
  float4 g1 = *(const float4*)(g + lane * 8 + 4);
  float4 b0 = *(const float4*)(b + lane * 8);
  float4 b1 = *(const float4*)(b + lane * 8 + 4);
  float gv[8] = {g0.x,g0.y,g0.z,g0.w,g1.x,g1.y,g1.z,g1.w};
  float bv[8] = {b0.x,b0.y,b0.z,b0.w,b1.x,b1.y,b1.z,b1.w};
  if (OUTF32) {
    float of[8];
    #pragma unroll
    for (int j = 0; j < 8; j++) of[j] = (xs[j] - mean) * rstd * gv[j] + bv[j];
    *(float4*)(outf + base)     = make_float4(of[0], of[1], of[2], of[3]);
    *(float4*)(outf + base + 4) = make_float4(of[4], of[5], of[6], of[7]);
  } else {
    v8u16 ob;
    #pragma unroll
    for (int j = 0; j < 8; j++) ob[j] = f2bf((xs[j] - mean) * rstd * gv[j] + bv[j]);
    *(v8u16*)(outb + base) = ob;
  }
}

// ---------------- GEMM core (r6-proven): acc[2][4] for a 64x128 tile, K=512, BK=64.
// Single-buffer global_load_lds staging, 2 barriers/K-step.
// LDS swizzle: granule g of row r stored at g^(r&7) (applied on global src + LDS read).
__device__ __forceinline__ void gemm_core(
    const u16* __restrict__ A, const u16* __restrict__ Wt,
    int m0, int n0, u16* As, u16* Bs, f32x4 (&acc)[2][4])
{
  int tid = threadIdx.x, wid = tid >> 6, lane = tid & 63;
  int wr = wid >> 1, wc = wid & 1;
  int l15 = lane & 15, hi = lane >> 4;
  int sr8 = lane >> 3;            // 0..7 row within 8-row group
  int gsw = (lane & 7) ^ sr8;     // swizzled source granule

  for (int s = 0; s < 8; s++) {
    int kk = s * 64;
    #pragma unroll
    for (int i = 0; i < 2; i++) {
      int rb = i * 32 + wid * 8;
      gload16(A + (size_t)(m0 + rb + sr8) * 512 + kk + gsw * 8, (char*)As + rb * 128);
    }
    #pragma unroll
    for (int j = 0; j < 4; j++) {
      int rb = j * 32 + wid * 8;
      gload16(Wt + (size_t)(n0 + rb + sr8) * 512 + kk + gsw * 8, (char*)Bs + rb * 128);
    }
    __syncthreads();
    #pragma unroll
    for (int ksub = 0; ksub < 2; ksub++) {
      int ga = ksub * 4 + hi;
      bf16x8 af[2], bfr[4];
      #pragma unroll
      for (int mi = 0; mi < 2; mi++) {
        int ra = wr * 32 + mi * 16 + l15;
        af[mi] = *(const bf16x8*)(As + ra * 64 + ((ga ^ (ra & 7)) * 8));
      }
      #pragma unroll
      for (int ni = 0; ni < 4; ni++) {
        int rb = wc * 64 + ni * 16 + l15;
        bfr[ni] = *(const bf16x8*)(Bs + rb * 64 + ((ga ^ (rb & 7)) * 8));
      }
      #pragma unroll
      for (int mi = 0; mi < 2; mi++)
        #pragma unroll
        for (int ni = 0; ni < 4; ni++)
          acc[mi][ni] = __builtin_amdgcn_mfma_f32_16x16x32_bf16(af[mi], bfr[ni], acc[mi][ni], 0, 0, 0);
    }
    __syncthreads();
  }
}

// single GEMM: grid 400 (100 M-tiles x 4 N-tiles)
template<bool RELU, bool HAS_RES, bool MASK>
__global__ __launch_bounds__(256) void gemm_one(
    const u16* __restrict__ A, const u16* __restrict__ Wt, const float* __restrict__ bias,
    const u16* __restrict__ res, const unsigned char* __restrict__ mask,
    u16* __restrict__ outb)
{
  __shared__ u16 As[64 * 64];
  __shared__ u16 Bs[128 * 64];
  int bid = blockIdx.x;
  int m0 = (bid >> 2) * 64, n0 = (bid & 3) * 128;
  f32x4 acc[2][4] = {};
  gemm_core(A, Wt, m0, n0, As, Bs, acc);

  int tid = threadIdx.x, wid = tid >> 6, lane = tid & 63;
  int wr = wid >> 1, wc = wid & 1;
  int l15 = lane & 15, hi = lane >> 4;
  #pragma unroll
  for (int ni = 0; ni < 4; ni++) {
    int gc = n0 + wc * 64 + ni * 16 + l15;
    float bvv = bias[gc];
    #pragma unroll
    for (int mi = 0; mi < 2; mi++) {
      int grb = m0 + wr * 32 + mi * 16 + hi * 4;
      #pragma unroll
      for (int r = 0; r < 4; r++) {
        int gr = grb + r;
        float v = acc[mi][ni][r] + bvv;
        if (HAS_RES) v += bf2f(res[(size_t)gr * 512 + gc]);
        if (RELU) v = fmaxf(v, 0.f);
        if (MASK) v = mask[gr] ? 0.f : v;
        outb[(size_t)gr * 512 + gc] = f2bf(v);
      }
    }
  }
}

// merged Q,K,V GEMMs: grid 1200. V written directly in transposed Vt layout.
__global__ __launch_bounds__(256) void gemm_qkv(
    const u16* __restrict__ Aq, const u16* __restrict__ Akv,
    const u16* __restrict__ Wtq, const u16* __restrict__ Wtk, const u16* __restrict__ Wtv,
    const float* __restrict__ bq, const float* __restrict__ bk, const float* __restrict__ bv,
    u16* __restrict__ outq, u16* __restrict__ outk, u16* __restrict__ outvt)
{
  __shared__ u16 As[64 * 64];
  __shared__ u16 Bs[128 * 64];
  int bid = blockIdx.x;
  int mat = bid / 400;
  int rr = bid - mat * 400;
  int m0 = (rr >> 2) * 64, n0 = (rr & 3) * 128;
  const u16*   A    = (mat == 0) ? Aq  : Akv;
  const u16*   Wt   = (mat == 0) ? Wtq : ((mat == 1) ? Wtk : Wtv);
  const float* bias = (mat == 0) ? bq  : ((mat == 1) ? bk  : bv);
  f32x4 acc[2][4] = {};
  gemm_core(A, Wt, m0, n0, As, Bs, acc);

  int tid = threadIdx.x, wid = tid >> 6, lane = tid & 63;
  int wr = wid >> 1, wc = wid & 1;
  int l15 = lane & 15, hi = lane >> 4;
  if (mat == 2) {
    // Vt[b,h,hd(64), l(224)] transposed write; pad cols [200,224) untouched (P is 0 there)
    #pragma unroll
    for (int ni = 0; ni < 4; ni++) {
      int gc = n0 + wc * 64 + ni * 16 + l15;
      float bvv = bias[gc];
      int h = gc >> 6, hd = gc & 63;
      #pragma unroll
      for (int mi = 0; mi < 2; mi++) {
        int grb = m0 + wr * 32 + mi * 16 + hi * 4;
        #pragma unroll
        for (int r = 0; r < 4; r++) {
          int gr = grb + r;
          int b = gr / 200, l = gr - b * 200;
          outvt[((size_t)(b * 8 + h) * 64 + hd) * 224 + l] = f2bf(acc[mi][ni][r] + bvv);
        }
      }
    }
  } else {
    u16* outb = (mat == 0) ? outq : outk;
    #pragma unroll
    for (int ni = 0; ni < 4; ni++) {
      int gc = n0 + wc * 64 + ni * 16 + l15;
      float bvv = bias[gc];
      #pragma unroll
      for (int mi = 0; mi < 2; mi++) {
        int grb = m0 + wr * 32 + mi * 16 + hi * 4;
        #pragma unroll
        for (int r = 0; r < 4; r++) {
          int gr = grb + r;
          outb[(size_t)gr * 512 + gc] = f2bf(acc[mi][ni][r] + bvv);
        }
      }
    }
  }
}

// ---------------- attention v3: 1 wave per WG, no K/V staging, 2 KB LDS P-slot.
// Grid 1792 = 256 (b,h) x 7 tile-pair slots, XCD-swizzled so all slots of one
// (b,h) share an XCD/L2. Slot s<6: tiles (12-s, s); s==6: tile 6 only.
__global__ __launch_bounds__(64) void attn_kernel(
    const u16* __restrict__ Qh, const u16* __restrict__ Kh,
    const u16* __restrict__ Vt, u16* __restrict__ ctx)
{
  __shared__ u16 Pb[2][16 * 32];
  int bid = blockIdx.x;
  int xcd = bid & 7, j = bid >> 3;
  int bh_hi = j / 7, s = j - bh_hi * 7;
  int bh = bh_hi * 8 + xcd;
  int b = bh >> 3, h = bh & 7;
  int lane = threadIdx.x;
  int l15 = lane & 15, hi = lane >> 4;

  const u16* Kg = Kh + (size_t)(b * L_) * D_ + h * HD_;
  const u16* Vg = Vt + (size_t)bh * 64 * 224;

  int tA = (s < 6) ? (12 - s) : 6;
  int tB = (s < 6) ? s : -1;

  for (int jj = 0; jj < 2; jj++) {
    int t = jj ? tB : tA;
    if (t < 0) break;
    int q0 = t * 16;
    int qrow = q0 + l15; if (qrow > L_ - 1) qrow = L_ - 1;
    const u16* Qg = Qh + (size_t)(b * L_ + qrow) * D_ + h * HD_ + hi * 8;
    bf16x8 aq0 = as_bf(*(const v8u16*)(Qg));
    bf16x8 aq1 = as_bf(*(const v8u16*)(Qg + 32));

    f32x4 sv[13];
    float m0[4];
    #pragma unroll
    for (int r = 0; r < 4; r++) m0[r] = -3.0e38f;

    #pragma unroll
    for (int kt = 0; kt < 13; kt++) {
      if (kt <= t) {                    // wave-uniform causal trim
        const u16* kp = Kg + (size_t)(kt * 16 + l15) * D_ + hi * 8;
        bf16x8 bk0 = as_bf(*(const v8u16*)(kp));
        bf16x8 bk1 = as_bf(*(const v8u16*)(kp + 32));
        f32x4 a = {0.f, 0.f, 0.f, 0.f};
        a = __builtin_amdgcn_mfma_f32_16x16x32_bf16(aq0, bk0, a, 0, 0, 0);
        a = __builtin_amdgcn_mfma_f32_16x16x32_bf16(aq1, bk1, a, 0, 0, 0);
        #pragma unroll
        for (int r = 0; r < 4; r++) {
          int qr = q0 + hi * 4 + r;
          int kc = kt * 16 + l15;
          float val = (kc <= qr && qr < L_) ? a[r] * 0.125f : -3.0e38f;
          sv[kt][r] = val;
          m0[r] = fmaxf(m0[r], val);
        }
      }
    }
    #pragma unroll
    for (int r = 0; r < 4; r++) {
      #pragma unroll
      for (int off = 1; off < 16; off <<= 1)
        m0[r] = fmaxf(m0[r], __shfl_xor(m0[r], off));
      if (m0[r] < -1e37f) m0[r] = 0.f;
    }
    float sum[4] = {0.f, 0.f, 0.f, 0.f};
    #pragma unroll
    for (int kt = 0; kt < 13; kt++) {
      if (kt <= t) {
        #pragma unroll
        for (int r = 0; r < 4; r++) {
          float p = __expf(sv[kt][r] - m0[r]);
          sv[kt][r] = p;
          sum[r] += p;
        }
      }
    }
    #pragma unroll
    for (int r = 0; r < 4; r++) {
      #pragma unroll
      for (int off = 1; off < 16; off <<= 1) sum[r] += __shfl_xor(sum[r], off);
    }
    float inv[4];
    #pragma unroll
    for (int r = 0; r < 4; r++) inv[r] = sum[r] > 0.f ? 1.f / sum[r] : 0.f;

    // PV: per 32-wide k-slot, bounce P through a 1 KB LDS slot (transpose),
    // V fragments read straight from global (L2-resident Vt).
    int ksmax = (t + 2) >> 1;
    f32x4 acc[4] = {};
    #pragma unroll
    for (int ks = 0; ks < 7; ks++) {
      if (ks < ksmax) {
        u16* Ps = (u16*)Pb[ks & 1];
        #pragma unroll
        for (int half = 0; half < 2; half++) {
          int kt = ks * 2 + half;
          #pragma unroll
          for (int r = 0; r < 4; r++) {
            float pv = (kt <= t) ? sv[kt][r] : 0.f;
            Ps[(hi * 4 + r) * 32 + half * 16 + l15] = f2bf(pv);
          }
        }
        bf16x8 ap = as_bf(*(const v8u16*)(Ps + l15 * 32 + hi * 8));
        #pragma unroll
        for (int nt = 0; nt < 4; nt++) {
          bf16x8 bv = as_bf(*(const v8u16*)(Vg + (nt * 16 + l15) * 224 + ks * 32 + hi * 8));
          acc[nt] = __builtin_amdgcn_mfma_f32_16x16x32_bf16(ap, bv, acc[nt], 0, 0, 0);
        }
      }
    }
    #pragma unroll
    for (int nt = 0; nt < 4; nt++) {
      #pragma unroll
      for (int r = 0; r < 4; r++) {
        int qr = q0 + hi * 4 + r;
        if (qr < L_) ctx[(size_t)(b * L_ + qr) * D_ + h * HD_ + nt * 16 + l15] = f2bf(acc[nt][r] * inv[r]);
      }
    }
  }
}

// ---------------- host ----------------
extern "C" void kernel_launch(void* const* d_in, const int* in_sizes, int n_in,
                              void* d_out, int out_size, void* d_ws, size_t ws_size,
                              hipStream_t stream)
{
  (void)in_sizes; (void)n_in; (void)out_size; (void)ws_size;
  const float* x    = (const float*)d_in[0];
  const unsigned char* mask = (const unsigned char*)d_in[1];
  const float* ln1g = (const float*)d_in[2];
  const float* ln1b = (const float*)d_in[3];
  const float* Wq   = (const float*)d_in[4];
  const float* bq   = (const float*)d_in[5];
  const float* Wk   = (const float*)d_in[6];
  const float* bk   = (const float*)d_in[7];
  const float* Wv   = (const float*)d_in[8];
  const float* bv   = (const float*)d_in[9];
  const float* Wo   = (const float*)d_in[10];
  const float* bo   = (const float*)d_in[11];
  const float* ln2g = (const float*)d_in[12];
  const float* ln2b = (const float*)d_in[13];
  const float* W1   = (const float*)d_in[14];
  const float* b1   = (const float*)d_in[15];
  const float* W2   = (const float*)d_in[16];
  const float* b2   = (const float*)d_in[17];
  const float* lnfg = (const float*)d_in[18];
  const float* lnfb = (const float*)d_in[19];

  char* ws = (char*)d_ws;
  u16* Wt  = (u16*)(ws);                 //  6,291,456 B
  u16* qb  = (u16*)(ws +  6291456);      //  6,553,600 B  current q (bf16)
  u16* Qn  = (u16*)(ws + 12845056);      //  6,553,600 B  LN output
  u16* qh  = (u16*)(ws + 19398656);      //  6,553,600 B  qh / h1
  u16* kh  = (u16*)(ws + 25952256);      //  6,553,600 B  kh
  u16* vh  = (u16*)(ws + 32505856);      //  6,553,600 B  ctx
  u16* Vtb = (u16*)(ws + 39059456);      //  7,340,032 B  -> end 46,399,488

  TPtrs tp;
  tp.s[0] = Wq; tp.s[1] = Wq + 262144;
  tp.s[2] = Wk; tp.s[3] = Wk + 262144;
  tp.s[4] = Wv; tp.s[5] = Wv + 262144;
  tp.s[6] = Wo; tp.s[7] = Wo + 262144;
  tp.s[8] = W1; tp.s[9] = W1 + 262144;
  tp.s[10] = W2; tp.s[11] = W2 + 262144;

  prep_kernel<<<dim3(2368), dim3(256), 0, stream>>>(x, mask, qb, tp, Wt);

  for (int i = 0; i < 2; i++) {
    const u16* Wtq = Wt + (size_t)(0 + i) * 262144;
    const u16* Wtk = Wt + (size_t)(2 + i) * 262144;
    const u16* Wtv = Wt + (size_t)(4 + i) * 262144;
    const u16* Wto = Wt + (size_t)(6 + i) * 262144;
    const u16* Wt1 = Wt + (size_t)(8 + i) * 262144;
    const u16* Wt2 = Wt + (size_t)(10 + i) * 262144;

    ln_kernel<false><<<dim3(1600), dim3(256), 0, stream>>>(qb, ln1g + i * 512, ln1b + i * 512, Qn, nullptr);
    gemm_qkv<<<dim3(1200), dim3(256), 0, stream>>>(Qn, qb, Wtq, Wtk, Wtv,
                                                   bq + i * 512, bk + i * 512, bv + i * 512,
                                                   qh, kh, Vtb);
    attn_kernel<<<dim3(1792), dim3(64), 0, stream>>>(qh, kh, Vtb, vh);   // ctx -> vh
    gemm_one<false,true,false><<<dim3(400), dim3(256), 0, stream>>>(vh, Wto, bo + i * 512, Qn, nullptr, qb);
    ln_kernel<false><<<dim3(1600), dim3(256), 0, stream>>>(qb, ln2g + i * 512, ln2b + i * 512, Qn, nullptr);
    gemm_one<true,false,false><<<dim3(400), dim3(256), 0, stream>>>(Qn, Wt1, b1 + i * 512, nullptr, nullptr, qh);
    gemm_one<false,true,true><<<dim3(400), dim3(256), 0, stream>>>(qh, Wt2, b2 + i * 512, Qn, mask, qb);
  }
  ln_kernel<true><<<dim3(1600), dim3(256), 0, stream>>>(qb, lnfg, lnfb, nullptr, (float*)d_out);
}